// Round 6
// baseline (440.389 us; speedup 1.0000x reference)
//
#include <hip/hip_runtime.h>

// Attention w/ deterministic JAX threefry dropout (p=0.9), scale = *8 (ref divides by D^-0.5).
// B=4 H=16 S=2048 D=64 fp32. History: R12 = 205us best (bf16x3 16x16x32, swizzled prepass image,
// single-buffer reg-prefetch, lazy stats, deferred phase B) -- MfmaUtil 22 / VALU 44 (incl MFMA)
// / LDS-serial ~67us / ~34% wait. R13 (hi-only screen + phase-B exact recompute) = 244us REGRESSION:
// moved work from idle matrix pipe to busy VALU/LDS pipes. Values must come from phase-A MFMA.
// R14: 32x32x16 MFMA reshape of R12. Waves own 32x32 quadrants (2 row-waves x 2 col-waves):
//   - LDS reads HALVE (8KB/wave-tile, 8 ds_read_b128 vs 16): 80 -> 48 KB/tile-block.
//   - matrix cycles -20% (12 MFMA x 8cyc vs 24 x 5cyc).
//   - staging/prepass/swizzle/prefetch byte-identical to R12 (verified).
//   - stats on verified 32x32 C layout (col=lane&31, row=(reg&3)+8(reg>>2)+4(lane>>5));
//     gate wave-local over 32 cols => candidate SUPERSET of R12's validated set (~12-16/row,
//     cap 44); values bf16x3, RNG bit-identical.
// LDS = 16384 (K) + 22528 (cand) + 256 + 512 = 39680 B -> 4 blocks/CU.
// Threefry2x32 key(0,42) xor-fold verified R4; 16x16 layouts verified R7; swizzle verified R10/R12.

typedef short short8 __attribute__((ext_vector_type(8)));
typedef float floatx16 __attribute__((ext_vector_type(16)));

#define S_LEN 2048
#define D_DIM 64
#define BM 64                 // Q rows per block
#define BN 64                 // K rows per j-tile
#define NTILES (S_LEN / BN)   // 32
#define E_THR 1e-7f
#define MARG 2.025f           // 16.2 logit units / 8 (acc units)
#define CAND_CAP 44           // ~12-16/row expected (2-way col-local gate); cap < 64 for phase B
#define K_ELEMS (64 * S_LEN * D_DIM)          // 8388608
#define WS_NEEDED ((size_t)K_ELEMS * 4)       // swizzled hi+lo bf16 planes = 33554432 B
#define TILE_BYTES 16384                      // [Kh 8192 | Kl 8192]
#define BH_BYTES (NTILES * TILE_BYTES)        // 524288

__device__ __forceinline__ unsigned int rotl32(unsigned int x, int n) {
  return (x << n) | (x >> (32 - n));
}

// JAX threefry2x32, key (0,42): ks=(0,42,0x1BD11BF0); counter (hi,lo)=(0,idx); 20 rounds;
// partitionable 32-bit output = x0 ^ x1 (verified bit-exact R4/R6/R7).
__device__ __forceinline__ unsigned int threefry_42_xorfold(unsigned int idx) {
  const unsigned int ks1 = 42u, ks2 = 0x1BD11BF0u;
  unsigned int x0 = 0u;
  unsigned int x1 = idx + ks1;
#define TF4(a, b, c, d)                          \
  x0 += x1; x1 = rotl32(x1, a); x1 ^= x0;        \
  x0 += x1; x1 = rotl32(x1, b); x1 ^= x0;        \
  x0 += x1; x1 = rotl32(x1, c); x1 ^= x0;        \
  x0 += x1; x1 = rotl32(x1, d); x1 ^= x0;
  TF4(13, 15, 26, 6)
  x0 += ks1; x1 += ks2 + 1u;
  TF4(17, 29, 16, 24)
  x0 += ks2; x1 += 2u;
  TF4(13, 15, 26, 6)
  x1 += ks1 + 3u;
  TF4(17, 29, 16, 24)
  x0 += ks1; x1 += ks2 + 4u;
  TF4(13, 15, 26, 6)
  x0 += ks2; x1 += 5u;
#undef TF4
  return x0 ^ x1;
}

// Truncation split of 4 fp32 -> packed bf16 hi (uint2) + bf16 lo (uint2).
// hi = x chopped to bf16 (round-toward-zero); lo = (x - hi) chopped. |x-hi-lo| <= 2^-16|x|.
__device__ __forceinline__ void split4(float4 x, uint2* hp, uint2* lop) {
  const unsigned int u0 = __float_as_uint(x.x), u1 = __float_as_uint(x.y);
  const unsigned int u2 = __float_as_uint(x.z), u3 = __float_as_uint(x.w);
  hp->x = (u0 >> 16) | (u1 & 0xFFFF0000u);
  hp->y = (u2 >> 16) | (u3 & 0xFFFF0000u);
  const float l0 = x.x - __uint_as_float(u0 & 0xFFFF0000u);
  const float l1 = x.y - __uint_as_float(u1 & 0xFFFF0000u);
  const float l2 = x.z - __uint_as_float(u2 & 0xFFFF0000u);
  const float l3 = x.w - __uint_as_float(u3 & 0xFFFF0000u);
  lop->x = (__float_as_uint(l0) >> 16) | (__float_as_uint(l1) & 0xFFFF0000u);
  lop->y = (__float_as_uint(l2) >> 16) | (__float_as_uint(l3) & 0xFFFF0000u);
}

// 8 contiguous fp32 -> short8 hi + short8 lo
__device__ __forceinline__ void split8(const float* x, short8* hi, short8* lo) {
  union { short8 s; uint2 u[2]; } h, l;
  split4(*(const float4*)(x + 0), &h.u[0], &l.u[0]);
  split4(*(const float4*)(x + 4), &h.u[1], &l.u[1]);
  *hi = h.s; *lo = l.s;
}

// ---- pre-pass: split K into the swizzled LDS tile image (identical to R12, verified) ----
// ws layout: [bh][tile][plane: Kh|Kl][row*128 + ((col8*16) ^ ((row&7)<<4))]
__global__ void split_k_kernel(const float* __restrict__ k, unsigned char* __restrict__ ws) {
  const int c = blockIdx.x * 256 + threadIdx.x;   // one 8-element chunk per thread
  const int bh = c >> 14;                          // 16384 chunks per bh
  const int cc = c & 16383;
  const int srow = cc >> 3, col8 = cc & 7;
  const int tile = srow >> 6, row = srow & 63;
  const float* src = k + ((size_t)bh * S_LEN + srow) * D_DIM + col8 * 8;
  float b8[8];
  *(float4*)&b8[0] = *(const float4*)src;
  *(float4*)&b8[4] = *(const float4*)(src + 4);
  short8 h, l;
  split8(b8, &h, &l);
  unsigned char* dst = ws + (size_t)bh * BH_BYTES + tile * TILE_BYTES +
                       row * 128 + ((col8 * 16) ^ ((row & 7) << 4));
  *(short8*)dst = h;
  *(short8*)(dst + 8192) = l;
}

__global__ __launch_bounds__(256, 4) void attn_dropout_kernel(
    const float* __restrict__ q, const float* __restrict__ k,
    const float* __restrict__ v, float* __restrict__ out,
    const unsigned char* __restrict__ kws, int usews) {
  __shared__ uint4 Kbuf[1024];              // 16384 B single buffer [Kh 8192 | Kl 8192]
  __shared__ float2 cand[BM][CAND_CAP];     // (8*acc value, col bits): 22528 B
  __shared__ int cnt[BM];
  __shared__ float rowm8w[2][BM];           // per-col-wave row maxes (x8), merged in phase B

  const int t = threadIdx.x;
  const int w = t >> 6;               // wave 0..3
  const int wr = w >> 1;              // row-wave: rows 32wr..32wr+31
  const int wc = w & 1;               // col-wave: cols 32wc..32wc+31
  const int lane = t & 63;
  const int l31 = lane & 31;          // A row / B col / C col within quadrant
  const int half = lane >> 5;         // k-halves for A/B; +4 rows for C
  const int i0 = blockIdx.x * BM;
  const int bh = blockIdx.y;          // 0..63

  const float* Qg = q + ((size_t)bh * S_LEN + i0) * D_DIM;
  const float* Kg = k + (size_t)bh * S_LEN * D_DIM;
  const float* Vg = v + (size_t)bh * S_LEN * D_DIM;

  if (t < BM) cnt[t] = 0;   // published by the first barrier below

  // ---- Q frags -> registers (A layout: row=lane&31, k = kk*16 + half*8 + e), bf16 hi/lo ----
  short8 qh[4], ql[4];
  {
    const int arow = 32 * wr + l31;
#pragma unroll
    for (int kk = 0; kk < 4; ++kk) {
      float qb[8];
      *(float4*)&qb[0] = *(const float4*)(Qg + arow * D_DIM + kk * 16 + half * 8);
      *(float4*)&qb[4] = *(const float4*)(Qg + arow * D_DIM + kk * 16 + half * 8 + 4);
      split8(qb, &qh[kk], &ql[kk]);
    }
  }

  float mrow[16];                     // running max (acc units) of MY half's row, per reg
#pragma unroll
  for (int r = 0; r < 16; ++r) mrow[r] = -1e30f;

  const unsigned int bh_base = (unsigned int)bh * (unsigned int)(S_LEN * S_LEN);

  // B-frag swizzled byte offsets (tile-invariant): B row (K col) = 32wc + l31
  const int brow = 32 * wc + l31;
  const int bswz = (brow & 7) << 4;
  int boff[4];
#pragma unroll
  for (int kk = 0; kk < 4; ++kk)
    boff[kk] = brow * 128 + ((kk * 32 + half * 16) ^ bswz);

  // ---- one tile: 12 MFMA (bf16x3, 32x32x16) + lazy stats/append ----
  auto compute_tile = [&](int j0) {
    const char* Kb = (const char*)&Kbuf[0];
    short8 kh[4], kl[4];
#pragma unroll
    for (int kk = 0; kk < 4; ++kk) {
      kh[kk] = *(const short8*)(Kb + boff[kk]);
      kl[kk] = *(const short8*)(Kb + 8192 + boff[kk]);
    }
    floatx16 a = {0.f, 0.f, 0.f, 0.f, 0.f, 0.f, 0.f, 0.f,
                  0.f, 0.f, 0.f, 0.f, 0.f, 0.f, 0.f, 0.f};
#pragma unroll
    for (int kk = 0; kk < 4; ++kk) {
      a = __builtin_amdgcn_mfma_f32_32x32x16_bf16(qh[kk], kh[kk], a, 0, 0, 0);
      a = __builtin_amdgcn_mfma_f32_32x32x16_bf16(qh[kk], kl[kk], a, 0, 0, 0);
      a = __builtin_amdgcn_mfma_f32_32x32x16_bf16(ql[kk], kh[kk], a, 0, 0, 0);
    }
    // lazy stats: per reg-group of 4, reduce+append only when a lane beats its row thr.
    // Gate untaken => group max <= mrow-MARG for every row => no append, no max change.
    const int col = j0 + 32 * wc + l31;     // this lane's column
#pragma unroll
    for (int g = 0; g < 4; ++g) {
      const float d0 = a[4 * g + 0] - mrow[4 * g + 0];
      const float d1 = a[4 * g + 1] - mrow[4 * g + 1];
      const float d2 = a[4 * g + 2] - mrow[4 * g + 2];
      const float d3 = a[4 * g + 3] - mrow[4 * g + 3];
      const float gm = fmaxf(fmaxf(d0, d1), fmaxf(d2, d3));
      if (__ballot(gm > -MARG)) {           // wave-uniform branch
#pragma unroll
        for (int rr = 0; rr < 4; ++rr) {
          const int reg = 4 * g + rr;
          float rmx = a[reg];
#pragma unroll
          for (int off = 1; off < 32; off <<= 1)
            rmx = fmaxf(rmx, __shfl_xor(rmx, off));   // xor<32: stays in my half -> my row
          const float mn = fmaxf(mrow[reg], rmx);
          mrow[reg] = mn;
          if (a[reg] > mn - MARG) {         // this lane's col qualifies for this row
            const int lrow = 32 * wr + (reg & 3) + 8 * (reg >> 2) + 4 * half;
            const int slot = atomicAdd(&cnt[lrow], 1);
            if (slot < CAND_CAP)
              cand[lrow][slot] = make_float2(8.f * a[reg],   // exact pow-2 scale
                                             __uint_as_float((unsigned int)col));
          }
        }
      }
    }
  };

  if (usews) {
    // ========== phase A: single-buffer, register-prefetch pipeline (R12-verified) ==========
    const uint4* gk = (const uint4*)(kws + (size_t)bh * BH_BYTES) + (w * 256 + lane);
    uint4* lp = &Kbuf[0] + (w * 256 + lane);
    uint4 r0 = gk[0], r1 = gk[64], r2 = gk[128], r3 = gk[192];   // tile 0

    for (int tile = 0; tile < NTILES; ++tile) {
      __syncthreads();                         // (A) prev tile's frag reads done
      lp[0] = r0; lp[64] = r1; lp[128] = r2; lp[192] = r3;
      __syncthreads();                         // (B) staging visible
      if (tile + 1 < NTILES) {                 // prefetch next; full compute phase to land
        const uint4* gp = gk + (size_t)(tile + 1) * 1024;
        r0 = gp[0]; r1 = gp[64]; r2 = gp[128]; r3 = gp[192];
      }
      compute_tile(tile * BN);
    }
  } else {
    // ========== fallback: in-kernel split from fp32 (writes swizzled layout) ==========
    for (int tile = 0; tile < NTILES; ++tile) {
      const int j0 = tile * BN;
      __syncthreads();
#pragma unroll
      for (int rr = 0; rr < 4; ++rr) {
        const int c = t + 256 * rr;            // 0..1023 float4 chunks, 16/row
        const int row = c >> 4, c4 = (c & 15) * 4;
        float4 x = *(const float4*)(Kg + (size_t)(j0 + row) * D_DIM + c4);
        uint2 h, l;
        split4(x, &h, &l);
        const int bcol = c4 * 2;               // byte col 0..120 step 8
        const int dst = row * 128 + ((bcol & ~15) ^ ((row & 7) << 4)) + (bcol & 15);
        char* Kb0 = (char*)&Kbuf[0];
        *(uint2*)(Kb0 + dst) = h;
        *(uint2*)(Kb0 + 8192 + dst) = l;
      }
      __syncthreads();
      compute_tile(j0);
    }
  }

  // publish per-row, per-col-wave maxes; lanes 0 and 32 hold the two halves' rows
  if (l31 == 0) {
#pragma unroll
    for (int reg = 0; reg < 16; ++reg)
      rowm8w[wc][32 * wr + (reg & 3) + 8 * (reg >> 2) + 4 * half] = 8.f * mrow[reg];
  }
  __syncthreads();

  // ========== phase B: per-row exp / threefry dropout / sparse PV (R12-verified) ==========
#pragma unroll 1
  for (int ri = 0; ri < 16; ++ri) {
    const int lrow = 16 * w + ri;               // wave-private rows
    const int ncand = min(cnt[lrow], CAND_CAP);
    const float m8 = fmaxf(rowm8w[0][lrow], rowm8w[1][lrow]);

    float e = 0.f;
    unsigned int col = 0u;
    if (lane < ncand) {
      const float2 cd = cand[lrow][lane];
      col = __float_as_uint(cd.y);
      e = __expf(cd.x - m8);
    }

    // denominator: sum over all candidates (drops only sub-e^-16.2-of-local-max terms)
    float lsum = e;
#pragma unroll
    for (int off = 1; off < 64; off <<= 1) lsum += __shfl_xor(lsum, off);
    lsum = fmaxf(lsum, 1e-30f);                 // NaN guard (cap overflow, astronomically rare)

    float p = 0.f;
    if (e > E_THR) {
      const unsigned int idx = bh_base +
          (unsigned int)(i0 + lrow) * (unsigned int)S_LEN + col;
      const unsigned int rr = threefry_42_xorfold(idx);
      const float u = __uint_as_float((rr >> 9) | 0x3f800000u) - 1.0f;
      if (u < 0.1f) p = e;
    }

    // sparse PV: broadcast kept (p,col); V row load is a coalesced 256B burst
    float o = 0.f;
    unsigned long long kb = __ballot(p != 0.f);
    while (kb) {
      const int src = __builtin_ctzll(kb);      // wave-uniform
      kb &= kb - 1;
      const float pb = __shfl(p, src);
      const int cb = __shfl((int)col, src);
      o = fmaf(pb, Vg[(size_t)cb * D_DIM + lane], o);
    }

    const float scale = 10.0f / lsum;           // ref: x / 0.1f
    out[((size_t)bh * S_LEN + i0 + lrow) * D_DIM + lane] = o * scale;
  }
}

extern "C" void kernel_launch(void* const* d_in, const int* in_sizes, int n_in,
                              void* d_out, int out_size, void* d_ws, size_t ws_size,
                              hipStream_t stream) {
  (void)in_sizes; (void)n_in;
  const float* q = (const float*)d_in[0];
  const float* k = (const float*)d_in[1];
  const float* v = (const float*)d_in[2];
  float* out = (float*)d_out;

  unsigned char* kws = (unsigned char*)d_ws;
  const int usews = (ws_size >= WS_NEEDED) ? 1 : 0;

  if (usews) {
    split_k_kernel<<<K_ELEMS / 8 / 256, 256, 0, stream>>>(k, kws);
  }
  dim3 grid(S_LEN / BM, 64);  // 32 i-tiles x (B*H=64)
  attn_dropout_kernel<<<grid, 256, 0, stream>>>(q, k, v, out, kws, usews);

  // Launch-failure beacon (absmax err ~100.8 instead of silent stale output).
  if (hipGetLastError() != hipSuccess) {
    hipMemsetAsync(d_out, 0x42, (size_t)out_size * sizeof(float), stream);
  }
}

// Round 7
// 341.686 us; speedup vs baseline: 1.2889x; 1.2889x over previous
//
#include <hip/hip_runtime.h>

// Attention w/ deterministic JAX threefry dropout (p=0.9), scale = *8 (ref divides by D^-0.5).
// B=4 H=16 S=2048 D=64 fp32. History: R12 = 205us best (bf16x3 16x16x32, swizzled prepass image,
// single-buffer reg-prefetch, lazy stats, deferred phase B; 4 blk/CU). R13 (screen+recompute)
// = 244us: moved work to busy VALU/LDS pipes. R14 (32x32 MFMA) = 364us: broke the verified
// conflict-free read shape (8.8M conflicts) + single dependent MFMA chain (no ILP).
// R15: 2x2 wave split with 16x16 MFMA kept. Wave (wr,wc) owns rows 32wr..+31 x cols 32wc..+31:
//   - LDS frag reads HALVE: 8KB/wave-tile (8 ds_read_b128), tile-block 80 -> 48 KB.
//   - read pattern = R12's verified 16-rows x 4-quad-cols shape ((brow&7)==(m16&7), same swizzle).
//   - MFMA: 4 independent chains of 6 (identical count + ILP to R12).
//   - staging/prepass/prefetch/phase-B identical to R12. Stats wave-local over 32 cols =>
//     candidate SUPERSET of validated set (~20/row); cand split into val(f32)+col(u16) arrays,
//     CAP 56. LDS = 16384 + 14336 + 7168 + 256 + 512 = 38656 B -> 4 blocks/CU.
// Threefry2x32 key(0,42) xor-fold verified R4; 16x16 layouts verified R7; swizzle verified R10/R12.

typedef short short8 __attribute__((ext_vector_type(8)));
typedef float floatx4 __attribute__((ext_vector_type(4)));

#define S_LEN 2048
#define D_DIM 64
#define BM 64                 // Q rows per block
#define BN 64                 // K rows per j-tile
#define NTILES (S_LEN / BN)   // 32
#define E_THR 1e-7f
#define MARG 2.025f           // 16.2 logit units / 8 (acc units)
#define CAND_CAP 56           // wave-local gate ~20/row expected; 6.8-sigma headroom
#define K_ELEMS (64 * S_LEN * D_DIM)          // 8388608
#define WS_NEEDED ((size_t)K_ELEMS * 4)       // swizzled hi+lo bf16 planes = 33554432 B
#define TILE_BYTES 16384                      // [Kh 8192 | Kl 8192]
#define BH_BYTES (NTILES * TILE_BYTES)        // 524288

__device__ __forceinline__ unsigned int rotl32(unsigned int x, int n) {
  return (x << n) | (x >> (32 - n));
}

// JAX threefry2x32, key (0,42): ks=(0,42,0x1BD11BF0); counter (hi,lo)=(0,idx); 20 rounds;
// partitionable 32-bit output = x0 ^ x1 (verified bit-exact R4/R6/R7).
__device__ __forceinline__ unsigned int threefry_42_xorfold(unsigned int idx) {
  const unsigned int ks1 = 42u, ks2 = 0x1BD11BF0u;
  unsigned int x0 = 0u;
  unsigned int x1 = idx + ks1;
#define TF4(a, b, c, d)                          \
  x0 += x1; x1 = rotl32(x1, a); x1 ^= x0;        \
  x0 += x1; x1 = rotl32(x1, b); x1 ^= x0;        \
  x0 += x1; x1 = rotl32(x1, c); x1 ^= x0;        \
  x0 += x1; x1 = rotl32(x1, d); x1 ^= x0;
  TF4(13, 15, 26, 6)
  x0 += ks1; x1 += ks2 + 1u;
  TF4(17, 29, 16, 24)
  x0 += ks2; x1 += 2u;
  TF4(13, 15, 26, 6)
  x1 += ks1 + 3u;
  TF4(17, 29, 16, 24)
  x0 += ks1; x1 += ks2 + 4u;
  TF4(13, 15, 26, 6)
  x0 += ks2; x1 += 5u;
#undef TF4
  return x0 ^ x1;
}

// Truncation split of 4 fp32 -> packed bf16 hi (uint2) + bf16 lo (uint2).
// hi = x chopped to bf16 (round-toward-zero); lo = (x - hi) chopped. |x-hi-lo| <= 2^-16|x|.
__device__ __forceinline__ void split4(float4 x, uint2* hp, uint2* lop) {
  const unsigned int u0 = __float_as_uint(x.x), u1 = __float_as_uint(x.y);
  const unsigned int u2 = __float_as_uint(x.z), u3 = __float_as_uint(x.w);
  hp->x = (u0 >> 16) | (u1 & 0xFFFF0000u);
  hp->y = (u2 >> 16) | (u3 & 0xFFFF0000u);
  const float l0 = x.x - __uint_as_float(u0 & 0xFFFF0000u);
  const float l1 = x.y - __uint_as_float(u1 & 0xFFFF0000u);
  const float l2 = x.z - __uint_as_float(u2 & 0xFFFF0000u);
  const float l3 = x.w - __uint_as_float(u3 & 0xFFFF0000u);
  lop->x = (__float_as_uint(l0) >> 16) | (__float_as_uint(l1) & 0xFFFF0000u);
  lop->y = (__float_as_uint(l2) >> 16) | (__float_as_uint(l3) & 0xFFFF0000u);
}

// 8 contiguous fp32 -> short8 hi + short8 lo
__device__ __forceinline__ void split8(const float* x, short8* hi, short8* lo) {
  union { short8 s; uint2 u[2]; } h, l;
  split4(*(const float4*)(x + 0), &h.u[0], &l.u[0]);
  split4(*(const float4*)(x + 4), &h.u[1], &l.u[1]);
  *hi = h.s; *lo = l.s;
}

// ---- pre-pass: split K into the swizzled LDS tile image (identical to R12, verified) ----
// ws layout: [bh][tile][plane: Kh|Kl][row*128 + ((col8*16) ^ ((row&7)<<4))]
__global__ void split_k_kernel(const float* __restrict__ k, unsigned char* __restrict__ ws) {
  const int c = blockIdx.x * 256 + threadIdx.x;   // one 8-element chunk per thread
  const int bh = c >> 14;                          // 16384 chunks per bh
  const int cc = c & 16383;
  const int srow = cc >> 3, col8 = cc & 7;
  const int tile = srow >> 6, row = srow & 63;
  const float* src = k + ((size_t)bh * S_LEN + srow) * D_DIM + col8 * 8;
  float b8[8];
  *(float4*)&b8[0] = *(const float4*)src;
  *(float4*)&b8[4] = *(const float4*)(src + 4);
  short8 h, l;
  split8(b8, &h, &l);
  unsigned char* dst = ws + (size_t)bh * BH_BYTES + tile * TILE_BYTES +
                       row * 128 + ((col8 * 16) ^ ((row & 7) << 4));
  *(short8*)dst = h;
  *(short8*)(dst + 8192) = l;
}

__global__ __launch_bounds__(256, 4) void attn_dropout_kernel(
    const float* __restrict__ q, const float* __restrict__ k,
    const float* __restrict__ v, float* __restrict__ out,
    const unsigned char* __restrict__ kws, int usews) {
  __shared__ uint4 Kbuf[1024];               // 16384 B single buffer [Kh 8192 | Kl 8192]
  __shared__ float candv[BM][CAND_CAP];      // candidate values (8*acc): 14336 B
  __shared__ unsigned short candc[BM][CAND_CAP];  // candidate cols: 7168 B
  __shared__ int cnt[BM];
  __shared__ float rowm8w[2][BM];            // per-col-wave row maxes (x8), merged in phase B

  const int t = threadIdx.x;
  const int w = t >> 6;               // wave 0..3
  const int wr = w >> 1;              // row-wave: rows 32wr..32wr+31
  const int wc = w & 1;               // col-wave: cols 32wc..32wc+31 of each tile
  const int m16 = t & 15;             // frag row select (A/B) and C col
  const int qd = (t & 63) >> 4;       // quad 0..3 -> C rows 4qd..4qd+3
  const int lane = t & 63;
  const int i0 = blockIdx.x * BM;
  const int bh = blockIdx.y;          // 0..63

  const float* Qg = q + ((size_t)bh * S_LEN + i0) * D_DIM;
  const float* Kg = k + (size_t)bh * S_LEN * D_DIM;
  const float* Vg = v + (size_t)bh * S_LEN * D_DIM;

  if (t < BM) cnt[t] = 0;   // published by the first barrier below

  // ---- Q frags -> registers, 2 rowsets (A layout: row=l&15, k=(l>>4)*8+j) ----
  short8 ah[2][2], al[2][2];          // [rowset][khalf]
#pragma unroll
  for (int rs = 0; rs < 2; ++rs) {
    const int arow = 32 * wr + 16 * rs + m16;
    float qbuf[8];
    *(float4*)&qbuf[0] = *(const float4*)(Qg + arow * D_DIM + qd * 8);
    *(float4*)&qbuf[4] = *(const float4*)(Qg + arow * D_DIM + qd * 8 + 4);
    split8(qbuf, &ah[rs][0], &al[rs][0]);
    *(float4*)&qbuf[0] = *(const float4*)(Qg + arow * D_DIM + 32 + qd * 8);
    *(float4*)&qbuf[4] = *(const float4*)(Qg + arow * D_DIM + 32 + qd * 8 + 4);
    split8(qbuf, &ah[rs][1], &al[rs][1]);
  }

  float mrow[2][4];                   // wave-local running max (acc units; logit = 8*acc)
#pragma unroll
  for (int rs = 0; rs < 2; ++rs)
#pragma unroll
    for (int r = 0; r < 4; ++r) mrow[rs][r] = -1e30f;

  const unsigned int bh_base = (unsigned int)bh * (unsigned int)(S_LEN * S_LEN);

  // B-frag swizzled byte offsets (tile-invariant). brow = 32wc+16jj+m16; since
  // 32wc+16jj == 0 mod 8, (brow&7)==(m16&7) -> exactly R12's verified conflict-free shape.
  const int swz = (m16 & 7) << 4;
  int boff[2][2];                     // [jj][khalf]
#pragma unroll
  for (int jj = 0; jj < 2; ++jj) {
    const int base = (32 * wc + 16 * jj + m16) * 128;
    boff[jj][0] = base + ((qd * 16) ^ swz);
    boff[jj][1] = base + ((qd * 16 + 64) ^ swz);
  }

  // ---- one tile: 24 MFMA (bf16x3, 4 independent chains of 6) + lazy stats/append ----
  auto compute_tile = [&](int j0) {
    const char* Kb = (const char*)&Kbuf[0];
    short8 kh[2][2], kl[2][2];        // [jj][khalf]
#pragma unroll
    for (int jj = 0; jj < 2; ++jj)
#pragma unroll
      for (int kk = 0; kk < 2; ++kk) {
        kh[jj][kk] = *(const short8*)(Kb + boff[jj][kk]);
        kl[jj][kk] = *(const short8*)(Kb + 8192 + boff[jj][kk]);
      }
    floatx4 acc[2][2];                // [rowset][jj]
#pragma unroll
    for (int rs = 0; rs < 2; ++rs)
#pragma unroll
      for (int jj = 0; jj < 2; ++jj) {
        floatx4 a = {0.f, 0.f, 0.f, 0.f};
        a = __builtin_amdgcn_mfma_f32_16x16x32_bf16(ah[rs][0], kh[jj][0], a, 0, 0, 0);
        a = __builtin_amdgcn_mfma_f32_16x16x32_bf16(ah[rs][1], kh[jj][1], a, 0, 0, 0);
        a = __builtin_amdgcn_mfma_f32_16x16x32_bf16(ah[rs][0], kl[jj][0], a, 0, 0, 0);
        a = __builtin_amdgcn_mfma_f32_16x16x32_bf16(ah[rs][1], kl[jj][1], a, 0, 0, 0);
        a = __builtin_amdgcn_mfma_f32_16x16x32_bf16(al[rs][0], kh[jj][0], a, 0, 0, 0);
        a = __builtin_amdgcn_mfma_f32_16x16x32_bf16(al[rs][1], kh[jj][1], a, 0, 0, 0);
        acc[rs][jj] = a;
      }
    // lazy stats (R12-verified): reduce+append only when a lane beats mrow-MARG.
    // Wave-local over 32 cols => candidate SUPERSET of the validated full-row-gate set.
#pragma unroll
    for (int rs = 0; rs < 2; ++rs) {
#pragma unroll
      for (int r = 0; r < 4; ++r) {
        const float rl = fmaxf(acc[rs][0][r], acc[rs][1][r]);
        const unsigned long long b = __ballot(rl > mrow[rs][r] - MARG);
        if ((b >> (16 * qd)) & 0xFFFFull) {     // uniform within the quad (quad = one row)
          float rmx = rl;
#pragma unroll
          for (int off = 1; off < 16; off <<= 1)
            rmx = fmaxf(rmx, __shfl_xor(rmx, off, 16));
          const float mn = fmaxf(mrow[rs][r], rmx);
          mrow[rs][r] = mn;
          const float thr = mn - MARG;
          const int lrow = 32 * wr + 16 * rs + 4 * qd + r;
#pragma unroll
          for (int jj = 0; jj < 2; ++jj) {
            if (acc[rs][jj][r] > thr) {
              const int slot = atomicAdd(&cnt[lrow], 1);
              if (slot < CAND_CAP) {
                candv[lrow][slot] = 8.f * acc[rs][jj][r];   // exact pow-2 scale
                candc[lrow][slot] = (unsigned short)(j0 + 32 * wc + 16 * jj + m16);
              }
            }
          }
        }
      }
    }
  };

  if (usews) {
    // ========== phase A: single-buffer, register-prefetch pipeline (R12-verified) ==========
    const uint4* gk = (const uint4*)(kws + (size_t)bh * BH_BYTES) + (w * 256 + lane);
    uint4* lp = &Kbuf[0] + (w * 256 + lane);
    uint4 r0 = gk[0], r1 = gk[64], r2 = gk[128], r3 = gk[192];   // tile 0

    for (int tile = 0; tile < NTILES; ++tile) {
      __syncthreads();                         // (A) prev tile's frag reads done
      lp[0] = r0; lp[64] = r1; lp[128] = r2; lp[192] = r3;
      __syncthreads();                         // (B) staging visible
      if (tile + 1 < NTILES) {                 // prefetch next; full compute phase to land
        const uint4* gp = gk + (size_t)(tile + 1) * 1024;
        r0 = gp[0]; r1 = gp[64]; r2 = gp[128]; r3 = gp[192];
      }
      compute_tile(tile * BN);
    }
  } else {
    // ========== fallback: in-kernel split from fp32 (writes swizzled layout) ==========
    for (int tile = 0; tile < NTILES; ++tile) {
      const int j0 = tile * BN;
      __syncthreads();
#pragma unroll
      for (int rr = 0; rr < 4; ++rr) {
        const int c = t + 256 * rr;            // 0..1023 float4 chunks, 16/row
        const int row = c >> 4, c4 = (c & 15) * 4;
        float4 x = *(const float4*)(Kg + (size_t)(j0 + row) * D_DIM + c4);
        uint2 h, l;
        split4(x, &h, &l);
        const int bcol = c4 * 2;               // byte col 0..120 step 8
        const int dst = row * 128 + ((bcol & ~15) ^ ((row & 7) << 4)) + (bcol & 15);
        char* Kb0 = (char*)&Kbuf[0];
        *(uint2*)(Kb0 + dst) = h;
        *(uint2*)(Kb0 + 8192 + dst) = l;
      }
      __syncthreads();
      compute_tile(j0);
    }
  }

  // publish per-row, per-col-wave maxes (lanes m16==0: qd 0..3 cover the 4 quad rows)
  if (m16 == 0) {
#pragma unroll
    for (int rs = 0; rs < 2; ++rs)
#pragma unroll
      for (int r = 0; r < 4; ++r)
        rowm8w[wc][32 * wr + 16 * rs + 4 * qd + r] = 8.f * mrow[rs][r];
  }
  __syncthreads();

  // ========== phase B: per-row exp / threefry dropout / sparse PV (R12-verified) ==========
#pragma unroll 1
  for (int ri = 0; ri < 16; ++ri) {
    const int lrow = 16 * w + ri;               // wave-private rows
    const int ncand = min(cnt[lrow], CAND_CAP);
    const float m8 = fmaxf(rowm8w[0][lrow], rowm8w[1][lrow]);

    float e = 0.f;
    unsigned int col = 0u;
    if (lane < ncand) {
      col = candc[lrow][lane];
      e = __expf(candv[lrow][lane] - m8);
    }

    // denominator: sum over all candidates (drops only sub-e^-16.2-of-local-max terms)
    float lsum = e;
#pragma unroll
    for (int off = 1; off < 64; off <<= 1) lsum += __shfl_xor(lsum, off);
    lsum = fmaxf(lsum, 1e-30f);                 // NaN guard (cap overflow, astronomically rare)

    float p = 0.f;
    if (e > E_THR) {
      const unsigned int idx = bh_base +
          (unsigned int)(i0 + lrow) * (unsigned int)S_LEN + col;
      const unsigned int rr = threefry_42_xorfold(idx);
      const float u = __uint_as_float((rr >> 9) | 0x3f800000u) - 1.0f;
      if (u < 0.1f) p = e;
    }

    // sparse PV: broadcast kept (p,col); V row load is a coalesced 256B burst
    float o = 0.f;
    unsigned long long kb = __ballot(p != 0.f);
    while (kb) {
      const int src = __builtin_ctzll(kb);      // wave-uniform
      kb &= kb - 1;
      const float pb = __shfl(p, src);
      const int cb = __shfl((int)col, src);
      o = fmaf(pb, Vg[(size_t)cb * D_DIM + lane], o);
    }

    const float scale = 10.0f / lsum;           // ref: x / 0.1f
    out[((size_t)bh * S_LEN + i0 + lrow) * D_DIM + lane] = o * scale;
  }
}

extern "C" void kernel_launch(void* const* d_in, const int* in_sizes, int n_in,
                              void* d_out, int out_size, void* d_ws, size_t ws_size,
                              hipStream_t stream) {
  (void)in_sizes; (void)n_in;
  const float* q = (const float*)d_in[0];
  const float* k = (const float*)d_in[1];
  const float* v = (const float*)d_in[2];
  float* out = (float*)d_out;

  unsigned char* kws = (unsigned char*)d_ws;
  const int usews = (ws_size >= WS_NEEDED) ? 1 : 0;

  if (usews) {
    split_k_kernel<<<K_ELEMS / 8 / 256, 256, 0, stream>>>(k, kws);
  }
  dim3 grid(S_LEN / BM, 64);  // 32 i-tiles x (B*H=64)
  attn_dropout_kernel<<<grid, 256, 0, stream>>>(q, k, v, out, kws, usews);

  // Launch-failure beacon (absmax err ~100.8 instead of silent stale output).
  if (hipGetLastError() != hipSuccess) {
    hipMemsetAsync(d_out, 0x42, (size_t)out_size * sizeof(float), stream);
  }
}

// Round 8
// 298.250 us; speedup vs baseline: 1.4766x; 1.1456x over previous
//
#include <hip/hip_runtime.h>

// Attention w/ deterministic JAX threefry dropout (p=0.9), scale = *8 (ref divides by D^-0.5).
// B=4 H=16 S=2048 D=64 fp32. History: R12 = 205us best (bf16x3 16x16x32 row-split, swizzled
// prepass image, single-buffer reg-prefetch, lazy stats, deferred phase B; 4 blk/CU, no pipe
// >44%). R13/R14/R15 all regressed: values must come from phase-A MFMA; 16x16 read shape +
// chain ILP are load-bearing; col-splits duplicate stats VALU. R16 = R12 bit-equivalent at
// 6 blocks/CU (latency-bound -> raise TLP):
//  (a) K-lo plane OUT of LDS: prepass stores lo in FRAG ORDER ([tile][jj][kk][lane*16]);
//      each wave reads lo as 8 coalesced 1KB global loads/tile from L2 (512KB/bh slice,
//      reused by 32 i-blocks). Wave-private -> no barrier, no staging, no LDS.
//      lo-consuming MFMAs last in each chain to hide L2 latency.
//  (b) staged hi tile halves to 8KB (2 uint4/thread copy); swizzled image + frag reads
//      unchanged (R10/R12-verified conflict-free).
//  (c) cand -> parallel f32 val + u16 col arrays (6B/entry, CAP 40 validated R9/R12).
// LDS = 8192 + 10240 + 5120 + 256 + 256 = 24064 B -> 6 blocks/CU. VGPR ~64 (<=85 ok for
// 6 waves/SIMD). Threefry2x32 key(0,42) xor-fold verified R4; 16x16 layouts verified R7.

typedef short short8 __attribute__((ext_vector_type(8)));
typedef float floatx4 __attribute__((ext_vector_type(4)));

#define S_LEN 2048
#define D_DIM 64
#define BM 64                 // Q rows per block: wave w owns rows 16w..16w+15
#define BN 64                 // K rows per j-tile: 4 sub-tiles (jj) of 16
#define NTILES (S_LEN / BN)   // 32
#define E_THR 1e-7f
#define MARG 2.025f           // 16.2 logit units / 8 (acc units)
#define CAND_CAP 40           // expected ~8 candidates/row (validated R9/R12)
#define K_ELEMS (64 * S_LEN * D_DIM)          // 8388608
#define WS_NEEDED ((size_t)K_ELEMS * 4)       // hi image + lo frag planes = 33554432 B
#define TILE_BYTES 16384                      // [hi image 8192 | lo frags 8192]
#define BH_BYTES (NTILES * TILE_BYTES)        // 524288

__device__ __forceinline__ unsigned int rotl32(unsigned int x, int n) {
  return (x << n) | (x >> (32 - n));
}

// JAX threefry2x32, key (0,42): ks=(0,42,0x1BD11BF0); counter (hi,lo)=(0,idx); 20 rounds;
// partitionable 32-bit output = x0 ^ x1 (verified bit-exact R4/R6/R7).
__device__ __forceinline__ unsigned int threefry_42_xorfold(unsigned int idx) {
  const unsigned int ks1 = 42u, ks2 = 0x1BD11BF0u;
  unsigned int x0 = 0u;
  unsigned int x1 = idx + ks1;
#define TF4(a, b, c, d)                          \
  x0 += x1; x1 = rotl32(x1, a); x1 ^= x0;        \
  x0 += x1; x1 = rotl32(x1, b); x1 ^= x0;        \
  x0 += x1; x1 = rotl32(x1, c); x1 ^= x0;        \
  x0 += x1; x1 = rotl32(x1, d); x1 ^= x0;
  TF4(13, 15, 26, 6)
  x0 += ks1; x1 += ks2 + 1u;
  TF4(17, 29, 16, 24)
  x0 += ks2; x1 += 2u;
  TF4(13, 15, 26, 6)
  x1 += ks1 + 3u;
  TF4(17, 29, 16, 24)
  x0 += ks1; x1 += ks2 + 4u;
  TF4(13, 15, 26, 6)
  x0 += ks2; x1 += 5u;
#undef TF4
  return x0 ^ x1;
}

// Truncation split of 4 fp32 -> packed bf16 hi (uint2) + bf16 lo (uint2).
// hi = x chopped to bf16 (round-toward-zero); lo = (x - hi) chopped. |x-hi-lo| <= 2^-16|x|.
__device__ __forceinline__ void split4(float4 x, uint2* hp, uint2* lop) {
  const unsigned int u0 = __float_as_uint(x.x), u1 = __float_as_uint(x.y);
  const unsigned int u2 = __float_as_uint(x.z), u3 = __float_as_uint(x.w);
  hp->x = (u0 >> 16) | (u1 & 0xFFFF0000u);
  hp->y = (u2 >> 16) | (u3 & 0xFFFF0000u);
  const float l0 = x.x - __uint_as_float(u0 & 0xFFFF0000u);
  const float l1 = x.y - __uint_as_float(u1 & 0xFFFF0000u);
  const float l2 = x.z - __uint_as_float(u2 & 0xFFFF0000u);
  const float l3 = x.w - __uint_as_float(u3 & 0xFFFF0000u);
  lop->x = (__float_as_uint(l0) >> 16) | (__float_as_uint(l1) & 0xFFFF0000u);
  lop->y = (__float_as_uint(l2) >> 16) | (__float_as_uint(l3) & 0xFFFF0000u);
}

// 8 contiguous fp32 -> short8 hi + short8 lo
__device__ __forceinline__ void split8(const float* x, short8* hi, short8* lo) {
  union { short8 s; uint2 u[2]; } h, l;
  split4(*(const float4*)(x + 0), &h.u[0], &l.u[0]);
  split4(*(const float4*)(x + 4), &h.u[1], &l.u[1]);
  *hi = h.s; *lo = l.s;
}

// ---- pre-pass: hi -> swizzled LDS image (R12-verified); lo -> frag-order plane ----
// hi: [bh][tile][row*128 + ((col8*16) ^ ((row&7)<<4))]
// lo: [bh][tile][8192 + jj*2048 + kk*1024 + lane*16], lane = (col8&3)*16 + (row&15)
__global__ void split_k_kernel(const float* __restrict__ k, unsigned char* __restrict__ ws) {
  const int c = blockIdx.x * 256 + threadIdx.x;   // one 8-element chunk per thread
  const int bh = c >> 14;                          // 16384 chunks per bh
  const int cc = c & 16383;
  const int srow = cc >> 3, col8 = cc & 7;
  const int tile = srow >> 6, row = srow & 63;
  const float* src = k + ((size_t)bh * S_LEN + srow) * D_DIM + col8 * 8;
  float b8[8];
  *(float4*)&b8[0] = *(const float4*)src;
  *(float4*)&b8[4] = *(const float4*)(src + 4);
  short8 h, l;
  split8(b8, &h, &l);
  unsigned char* base = ws + (size_t)bh * BH_BYTES + tile * TILE_BYTES;
  *(short8*)(base + row * 128 + ((col8 * 16) ^ ((row & 7) << 4))) = h;
  const int jj = row >> 4, kk = col8 >> 2;
  const int lane = (col8 & 3) * 16 + (row & 15);
  *(short8*)(base + 8192 + jj * 2048 + kk * 1024 + lane * 16) = l;
}

__global__ __launch_bounds__(256, 6) void attn_dropout_kernel(
    const float* __restrict__ q, const float* __restrict__ k,
    const float* __restrict__ v, float* __restrict__ out,
    const unsigned char* __restrict__ kws, int usews) {
  __shared__ uint4 Kbuf[512];                     // 8192 B: swizzled hi image
  __shared__ float candv[BM][CAND_CAP];           // 10240 B: candidate values (8*acc)
  __shared__ unsigned short candc[BM][CAND_CAP];  // 5120 B: candidate cols
  __shared__ int cnt[BM];
  __shared__ float rowm8[BM];

  const int t = threadIdx.x;
  const int w = t >> 6;               // wave 0..3 -> rows 16w..16w+15
  const int m16 = t & 15;             // frag row select (A/B) and C col
  const int qd = (t & 63) >> 4;       // quad 0..3 -> C rows 4qd..4qd+3
  const int lane = t & 63;
  const int i0 = blockIdx.x * BM;
  const int bh = blockIdx.y;          // 0..63

  const float* Qg = q + ((size_t)bh * S_LEN + i0) * D_DIM;
  const float* Kg = k + (size_t)bh * S_LEN * D_DIM;
  const float* Vg = v + (size_t)bh * S_LEN * D_DIM;

  if (t < BM) cnt[t] = 0;   // published by the first barrier below

  // ---- Q fragments -> registers, once (A layout: row=l&15, k=(l>>4)*8+j) ----
  short8 ah0, ah1, al0, al1;
  {
    const int arow = 16 * w + m16;
    float qbuf[8];
    *(float4*)&qbuf[0] = *(const float4*)(Qg + arow * D_DIM + qd * 8);
    *(float4*)&qbuf[4] = *(const float4*)(Qg + arow * D_DIM + qd * 8 + 4);
    split8(qbuf, &ah0, &al0);
    *(float4*)&qbuf[0] = *(const float4*)(Qg + arow * D_DIM + 32 + qd * 8);
    *(float4*)&qbuf[4] = *(const float4*)(Qg + arow * D_DIM + 32 + qd * 8 + 4);
    split8(qbuf, &ah1, &al1);
  }

  float mrow[4];                      // running max in acc units (logit = 8*acc)
#pragma unroll
  for (int r = 0; r < 4; ++r) mrow[r] = -1e30f;

  const unsigned int bh_base = (unsigned int)bh * (unsigned int)(S_LEN * S_LEN);

  // per-lane swizzled frag-read byte bases (tile-invariant): row = 16jj + m16
  const int swz = (m16 & 7) << 4;
  const int b_lo = m16 * 128 + ((qd * 16) ^ swz);
  const int b_hi = m16 * 128 + ((qd * 16 + 64) ^ swz);

  // ---- lazy per-row stats + append (R12-verified, values/gate identical) ----
  auto do_stats = [&](const floatx4* acc, int j0) {
#pragma unroll
    for (int r = 0; r < 4; ++r) {
      const float rl = fmaxf(fmaxf(acc[0][r], acc[1][r]), fmaxf(acc[2][r], acc[3][r]));
      const unsigned long long b = __ballot(rl > mrow[r] - MARG);
      if ((b >> (16 * qd)) & 0xFFFFull) {       // uniform within the quad (quad = one row)
        float rmx = rl;
#pragma unroll
        for (int off = 1; off < 16; off <<= 1)
          rmx = fmaxf(rmx, __shfl_xor(rmx, off, 16));
        const float mn = fmaxf(mrow[r], rmx);
        mrow[r] = mn;
        const float thr = mn - MARG;
        const int lrow = 16 * w + 4 * qd + r;
#pragma unroll
        for (int jj = 0; jj < 4; ++jj) {
          if (acc[jj][r] > thr) {
            const int slot = atomicAdd(&cnt[lrow], 1);
            if (slot < CAND_CAP) {
              candv[lrow][slot] = 8.f * acc[jj][r];   // exact pow-2 scale
              candc[lrow][slot] = (unsigned short)(j0 + 16 * jj + m16);
            }
          }
        }
      }
    }
  };

  if (usews) {
    // ===== phase A: hi staged (8KB, reg-prefetch, R12 pipeline); lo direct from L2 =====
    const uint4* gk = (const uint4*)(kws + (size_t)bh * BH_BYTES) + t;  // tile stride 1024
    uint4* lp = &Kbuf[0] + t;
    uint4 r0 = gk[0], r1 = gk[256];                                     // tile 0 hi

    for (int tile = 0; tile < NTILES; ++tile) {
      __syncthreads();                         // (A) prev tile's frag reads done
      lp[0] = r0; lp[256] = r1;
      __syncthreads();                         // (B) staging visible
      if (tile + 1 < NTILES) {                 // prefetch next hi; full compute phase to land
        const uint4* gp = gk + (size_t)(tile + 1) * 1024;
        r0 = gp[0]; r1 = gp[256];
      }
      const char* Kb = (const char*)&Kbuf[0];
      const char* lob = (const char*)kws + (size_t)bh * BH_BYTES + tile * TILE_BYTES + 8192;
      floatx4 acc[4];
#pragma unroll
      for (int jj = 0; jj < 4; ++jj) {
        // lo frags: coalesced 1KB global loads (L2-hot), wave-private, no barrier
        short8 kl0 = *(const short8*)(lob + jj * 2048 + lane * 16);
        short8 kl1 = *(const short8*)(lob + jj * 2048 + 1024 + lane * 16);
        short8 kh0 = *(const short8*)(Kb + jj * 2048 + b_lo);
        short8 kh1 = *(const short8*)(Kb + jj * 2048 + b_hi);
        floatx4 a = {0.f, 0.f, 0.f, 0.f};
        a = __builtin_amdgcn_mfma_f32_16x16x32_bf16(ah0, kh0, a, 0, 0, 0);
        a = __builtin_amdgcn_mfma_f32_16x16x32_bf16(ah1, kh1, a, 0, 0, 0);
        a = __builtin_amdgcn_mfma_f32_16x16x32_bf16(al0, kh0, a, 0, 0, 0);
        a = __builtin_amdgcn_mfma_f32_16x16x32_bf16(al1, kh1, a, 0, 0, 0);
        a = __builtin_amdgcn_mfma_f32_16x16x32_bf16(ah0, kl0, a, 0, 0, 0);  // lo last:
        a = __builtin_amdgcn_mfma_f32_16x16x32_bf16(ah1, kl1, a, 0, 0, 0);  // hides L2 lat
        acc[jj] = a;
      }
      do_stats(acc, tile * BN);
    }
  } else {
    // ===== fallback (ws too small): all-register fp32 split per wave, no staging =====
    __syncthreads();                           // cnt visible
    for (int tile = 0; tile < NTILES; ++tile) {
      floatx4 acc[4];
#pragma unroll
      for (int jj = 0; jj < 4; ++jj) {
        const float* kp = Kg + (size_t)(tile * BN + 16 * jj + m16) * D_DIM + qd * 8;
        float b8[8];
        short8 kh0, kh1, kl0, kl1;
        *(float4*)&b8[0] = *(const float4*)kp;
        *(float4*)&b8[4] = *(const float4*)(kp + 4);
        split8(b8, &kh0, &kl0);
        *(float4*)&b8[0] = *(const float4*)(kp + 32);
        *(float4*)&b8[4] = *(const float4*)(kp + 36);
        split8(b8, &kh1, &kl1);
        floatx4 a = {0.f, 0.f, 0.f, 0.f};
        a = __builtin_amdgcn_mfma_f32_16x16x32_bf16(ah0, kh0, a, 0, 0, 0);
        a = __builtin_amdgcn_mfma_f32_16x16x32_bf16(ah1, kh1, a, 0, 0, 0);
        a = __builtin_amdgcn_mfma_f32_16x16x32_bf16(al0, kh0, a, 0, 0, 0);
        a = __builtin_amdgcn_mfma_f32_16x16x32_bf16(al1, kh1, a, 0, 0, 0);
        a = __builtin_amdgcn_mfma_f32_16x16x32_bf16(ah0, kl0, a, 0, 0, 0);
        a = __builtin_amdgcn_mfma_f32_16x16x32_bf16(ah1, kl1, a, 0, 0, 0);
        acc[jj] = a;
      }
      do_stats(acc, tile * BN);
    }
  }

  // publish per-row final max (quad-coherent by construction)
  if (m16 == 0) {
#pragma unroll
    for (int r = 0; r < 4; ++r) rowm8[16 * w + 4 * qd + r] = 8.f * mrow[r];
  }
  __syncthreads();

  // ========== phase B: per-row exp / threefry dropout / sparse PV (R12-verified) ==========
#pragma unroll 1
  for (int ri = 0; ri < 16; ++ri) {
    const int lrow = 16 * w + ri;               // wave-private rows
    const int ncand = min(cnt[lrow], CAND_CAP);
    const float m8 = rowm8[lrow];

    float e = 0.f;
    unsigned int col = 0u;
    if (lane < ncand) {
      col = candc[lrow][lane];
      e = __expf(candv[lrow][lane] - m8);
    }

    // denominator: sum over all candidates (drops only sub-e^-16.2 terms)
    float lsum = e;
#pragma unroll
    for (int off = 1; off < 64; off <<= 1) lsum += __shfl_xor(lsum, off);
    lsum = fmaxf(lsum, 1e-30f);                 // NaN guard (cap overflow, astronomically rare)

    float p = 0.f;
    if (e > E_THR) {
      const unsigned int idx = bh_base +
          (unsigned int)(i0 + lrow) * (unsigned int)S_LEN + col;
      const unsigned int rr = threefry_42_xorfold(idx);
      const float u = __uint_as_float((rr >> 9) | 0x3f800000u) - 1.0f;
      if (u < 0.1f) p = e;
    }

    // sparse PV: broadcast kept (p,col); V row load is a coalesced 256B burst
    float o = 0.f;
    unsigned long long kb = __ballot(p != 0.f);
    while (kb) {
      const int src = __builtin_ctzll(kb);      // wave-uniform
      kb &= kb - 1;
      const float pb = __shfl(p, src);
      const int cb = __shfl((int)col, src);
      o = fmaf(pb, Vg[(size_t)cb * D_DIM + lane], o);
    }

    const float scale = 10.0f / lsum;           // ref: x / 0.1f
    out[((size_t)bh * S_LEN + i0 + lrow) * D_DIM + lane] = o * scale;
  }
}

extern "C" void kernel_launch(void* const* d_in, const int* in_sizes, int n_in,
                              void* d_out, int out_size, void* d_ws, size_t ws_size,
                              hipStream_t stream) {
  (void)in_sizes; (void)n_in;
  const float* q = (const float*)d_in[0];
  const float* k = (const float*)d_in[1];
  const float* v = (const float*)d_in[2];
  float* out = (float*)d_out;

  unsigned char* kws = (unsigned char*)d_ws;
  const int usews = (ws_size >= WS_NEEDED) ? 1 : 0;

  if (usews) {
    split_k_kernel<<<K_ELEMS / 8 / 256, 256, 0, stream>>>(k, kws);
  }
  dim3 grid(S_LEN / BM, 64);  // 32 i-tiles x (B*H=64)
  attn_dropout_kernel<<<grid, 256, 0, stream>>>(q, k, v, out, kws, usews);

  // Launch-failure beacon (absmax err ~100.8 instead of silent stale output).
  if (hipGetLastError() != hipSuccess) {
    hipMemsetAsync(d_out, 0x42, (size_t)out_size * sizeof(float), stream);
  }
}